// Round 12
// baseline (242.874 us; speedup 1.0000x reference)
//
#include <hip/hip_runtime.h>
#include <hip/hip_fp16.h>
#include <math.h>

#define N 20000
#define NPAD 20032
#define F 128
#define C1 256   // HEADS*HIDDEN
#define HEADS 8
#define HID 32
#define NC 40
#define NEG 0.2f

#define BSHIFT 7
#define NB 157        // buckets of 128 nodes
#define HBLOCKS 256
#define HM (NB * HBLOCKS)

#define PREPX_BLOCKS 2504
#define PREPW_BLOCKS 16

typedef _Float16 half8 __attribute__((ext_vector_type(8)));
typedef _Float16 half4v __attribute__((ext_vector_type(4)));
typedef float f32x4 __attribute__((ext_vector_type(4)));

__device__ __forceinline__ int edge_stride(const int* ei) {
    return (ei[1] == 0 && ei[3] == 0 && ei[5] == 0 && ei[7] == 0 && ei[9] == 0) ? 2 : 1;
}

__device__ __forceinline__ float lrelu(float v) { return v > 0.f ? v : NEG * v; }

// ---- K0: fused prep_x, prep_w, bucket histogram (LDS atomics only)
__global__ __launch_bounds__(256) void k_misc(
    const float* __restrict__ x, _Float16* __restrict__ xh,
    const float* __restrict__ W1, _Float16* __restrict__ w1sw,
    const int* __restrict__ ei, int E, int* __restrict__ hist)
{
    const int b = blockIdx.x;
    const int tid = threadIdx.x;
    if (b < PREPX_BLOCKS) {
        const int idx = (b * 256 + tid) * 4;
        half4v o;
        if (idx < N * F) {
            const float4 v = *reinterpret_cast<const float4*>(&x[idx]);
            o[0] = (_Float16)v.x; o[1] = (_Float16)v.y; o[2] = (_Float16)v.z; o[3] = (_Float16)v.w;
        } else {
            o[0] = (_Float16)0.f; o[1] = (_Float16)0.f; o[2] = (_Float16)0.f; o[3] = (_Float16)0.f;
        }
        *reinterpret_cast<half4v*>(&xh[idx]) = o;
    } else if (b < PREPX_BLOCKS + PREPW_BLOCKS) {
        const int slot = (b - PREPX_BLOCKS) * 256 + tid;
        const int lane = slot & 63;
        const int tile = slot >> 6;
        const int nt = tile & 15, ks = tile >> 4;
        const int n = nt * 16 + (lane & 15);
        const int k0 = ks * 32 + (lane >> 4) * 8;
        half8 tmp;
#pragma unroll
        for (int j = 0; j < 8; j++) tmp[j] = (_Float16)W1[(k0 + j) * C1 + n];
        *reinterpret_cast<half8*>(&w1sw[(size_t)slot * 8]) = tmp;
    } else {
        __shared__ int hcnt[NB];
        const int hb = b - PREPX_BLOCKS - PREPW_BLOCKS;
        if (tid < NB) hcnt[tid] = 0;
        __syncthreads();
        const int ET = E + N;
        const int per = (ET + HBLOCKS - 1) / HBLOCKS;
        const int lo = hb * per;
        const int hi = (lo + per < ET) ? (lo + per) : ET;
        const int st = edge_stride(ei);
        for (int i = lo + tid; i < hi; i += 256) {
            const int d = (i < E) ? ei[(size_t)st * (E + i)] : (i - E);
            atomicAdd(&hcnt[d >> BSHIFT], 1);
        }
        __syncthreads();
        if (tid < NB) hist[tid * HBLOCKS + hb] = hcnt[tid];
    }
}

// ---- K1: h1 = x @ W1 via MFMA; fused as1/ad1 projections.
__global__ __launch_bounds__(256) void k_gemm1_mfma(
    const _Float16* __restrict__ xh, const _Float16* __restrict__ w1sw,
    const float* __restrict__ a1s, const float* __restrict__ a1d,
    __half* __restrict__ h1h, float* __restrict__ as1, float* __restrict__ ad1)
{
    const int lane = threadIdx.x & 63;
    const int wid = (blockIdx.x * 256 + threadIdx.x) >> 6;
    const int m0 = wid * 16;
    const int g = lane >> 4, lm = lane & 15;
    half8 a[4];
    const size_t arow = (size_t)(m0 + lm) * F;
#pragma unroll
    for (int ks = 0; ks < 4; ks++)
        a[ks] = *reinterpret_cast<const half8*>(&xh[arow + ks * 32 + g * 8]);
    const int rbase = m0 + g * 4;
    float ps[4] = {0.f, 0.f, 0.f, 0.f}, pd[4] = {0.f, 0.f, 0.f, 0.f};
#pragma unroll
    for (int nt = 0; nt < 16; nt++) {
        f32x4 acc = {0.f, 0.f, 0.f, 0.f};
#pragma unroll
        for (int ks = 0; ks < 4; ks++) {
            const half8 bfr = *reinterpret_cast<const half8*>(&w1sw[(size_t)((ks * 16 + nt) * 64 + lane) * 8]);
            acc = __builtin_amdgcn_mfma_f32_16x16x32_f16(a[ks], bfr, acc, 0, 0, 0);
        }
        const int col = nt * 16 + lm;
        const float av = a1s[col], dv = a1d[col];
#pragma unroll
        for (int r = 0; r < 4; r++) {
            const int row = rbase + r;
            if (row < N) h1h[(size_t)row * C1 + col] = __float2half((float)acc[r]);
            ps[r] = fmaf((float)acc[r], av, ps[r]);
            pd[r] = fmaf((float)acc[r], dv, pd[r]);
        }
        if (nt & 1) {
#pragma unroll
            for (int off = 1; off <= 8; off <<= 1) {
#pragma unroll
                for (int r = 0; r < 4; r++) {
                    ps[r] += __shfl_xor(ps[r], off);
                    pd[r] += __shfl_xor(pd[r], off);
                }
            }
            if (lm == 0) {
                const int head = nt >> 1;
#pragma unroll
                for (int r = 0; r < 4; r++) {
                    const int row = rbase + r;
                    if (row < N) {
                        as1[row * HEADS + head] = ps[r];
                        ad1[row * HEADS + head] = pd[r];
                    }
                }
            }
#pragma unroll
            for (int r = 0; r < 4; r++) { ps[r] = 0.f; pd[r] = 0.f; }
        }
    }
}

// ---- K2a: per-bucket sums (157 blocks x 256 thr)
__global__ __launch_bounds__(256) void k_bsum(const int* __restrict__ hist,
                                              int* __restrict__ bsum)
{
    __shared__ int wsum[4];
    const int b = blockIdx.x;
    const int tid = threadIdx.x;
    const int lane = tid & 63, wid = tid >> 6;
    int v = hist[b * HBLOCKS + tid];
#pragma unroll
    for (int off = 32; off >= 1; off >>= 1) v += __shfl_xor(v, off);
    if (lane == 0) wsum[wid] = v;
    __syncthreads();
    if (tid == 0) bsum[b] = wsum[0] + wsum[1] + wsum[2] + wsum[3];
}

// ---- K2b: exclusive scan of bsum[157] in place. One block.
__global__ __launch_bounds__(256) void k_bscan(int* __restrict__ bsum)
{
    __shared__ int wbase[4];
    const int t = threadIdx.x;
    const int lane = t & 63, wid = t >> 6;
    const int vin = (t < NB) ? bsum[t] : 0;
    int v = vin;
#pragma unroll
    for (int off = 1; off < 64; off <<= 1) {
        const int u = __shfl_up(v, off, 64);
        if (lane >= off) v += u;
    }
    if (lane == 63) wbase[wid] = v;
    __syncthreads();
    if (t < 64) {
        int w = (lane < 4) ? wbase[lane] : 0;
        const int orig = w;
#pragma unroll
        for (int off = 1; off < 4; off <<= 1) {
            const int u = __shfl_up(w, off, 64);
            if (lane >= off) w += u;
        }
        if (lane < 4) wbase[lane] = w - orig;
    }
    __syncthreads();
    if (t < NB) bsum[t] = wbase[wid] + v - vin;   // exclusive
}

// ---- K2c: per-bucket exclusive scan + bucket base -> hist in place.
__global__ __launch_bounds__(256) void k_hscan(int* __restrict__ hist,
                                               const int* __restrict__ bsum)
{
    __shared__ int wbase[4];
    const int b = blockIdx.x;
    const int tid = threadIdx.x;
    const int lane = tid & 63, wid = tid >> 6;
    const int vin = hist[b * HBLOCKS + tid];
    int v = vin;
#pragma unroll
    for (int off = 1; off < 64; off <<= 1) {
        const int u = __shfl_up(v, off, 64);
        if (lane >= off) v += u;
    }
    if (lane == 63) wbase[wid] = v;
    __syncthreads();
    if (tid < 64) {
        int w = (lane < 4) ? wbase[lane] : 0;
        const int orig = w;
#pragma unroll
        for (int off = 1; off < 4; off <<= 1) {
            const int u = __shfl_up(w, off, 64);
            if (lane >= off) w += u;
        }
        if (lane < 4) wbase[lane] = w - orig;
    }
    __syncthreads();
    hist[b * HBLOCKS + tid] = bsum[b] + wbase[wid] + v - vin;
}

// ---- K3: scatter edges into coarse buckets. LDS cursors only.
__global__ __launch_bounds__(256) void k_scatter(
    const int* __restrict__ ei, int E, const int* __restrict__ hist,
    int* __restrict__ buck)
{
    __shared__ int cur[NB];
    const int hb = blockIdx.x;
    const int tid = threadIdx.x;
    if (tid < NB) cur[tid] = hist[tid * HBLOCKS + hb];
    __syncthreads();
    const int ET = E + N;
    const int per = (ET + HBLOCKS - 1) / HBLOCKS;
    const int lo = hb * per;
    const int hi = (lo + per < ET) ? (lo + per) : ET;
    const int st = edge_stride(ei);
    for (int i = lo + tid; i < hi; i += 256) {
        int s, d;
        if (i < E) { s = ei[(size_t)st * i]; d = ei[(size_t)st * (E + i)]; }
        else       { s = i - E; d = i - E; }
        const int slot = atomicAdd(&cur[d >> BSHIFT], 1);
        buck[slot] = ((d & 127) << 16) | s;
    }
}

// ---- K4: per-bucket counting sort -> csr + rowptr + fused edge weights wc1.
__global__ __launch_bounds__(256) void k_bucket(
    const int* __restrict__ hist, const int* __restrict__ buck, int ET,
    const float* __restrict__ as1, const float* __restrict__ ad1,
    int* __restrict__ csr, int* __restrict__ rowptr, __half* __restrict__ wc1)
{
    __shared__ int cnt[128];
    __shared__ int pfx[128];
    const int b = blockIdx.x;
    const int tid = threadIdx.x;
    const int start = hist[b * HBLOCKS];
    const int end = (b == NB - 1) ? ET : hist[(b + 1) * HBLOCKS];
    if (tid < 128) cnt[tid] = 0;
    __syncthreads();
    for (int i = start + tid; i < end; i += 256)
        atomicAdd(&cnt[buck[i] >> 16], 1);
    __syncthreads();
    if (tid < 128) pfx[tid] = cnt[tid];
    __syncthreads();
    for (int off = 1; off < 128; off <<= 1) {
        int u = 0;
        if (tid < 128 && tid >= off) u = pfx[tid - off];
        __syncthreads();
        if (tid < 128) pfx[tid] += u;
        __syncthreads();
    }
    if (tid < 128) {
        const int node = b * 128 + tid;
        const int ebase = start + pfx[tid] - cnt[tid];
        if (node < N) rowptr[node] = ebase;
        cnt[tid] = ebase;
    }
    if (b == NB - 1 && tid == 0) rowptr[N] = ET;
    __syncthreads();
    for (int i = start + tid; i < end; i += 256) {
        const int val = buck[i];
        const int loc = val >> 16;
        const int s = val & 0xFFFF;
        const int d = b * 128 + loc;
        const int slot = atomicAdd(&cnt[loc], 1);
        csr[slot] = s;
        const float4 a0 = *reinterpret_cast<const float4*>(&as1[s * HEADS]);
        const float4 a1v = *reinterpret_cast<const float4*>(&as1[s * HEADS + 4]);
        const float4 b0 = *reinterpret_cast<const float4*>(&ad1[d * HEADS]);
        const float4 b1v = *reinterpret_cast<const float4*>(&ad1[d * HEADS + 4]);
        union { float4 f4; __half2 h2[4]; } u;
        u.h2[0] = __floats2half2_rn(__expf(lrelu(a0.x + b0.x)), __expf(lrelu(a0.y + b0.y)));
        u.h2[1] = __floats2half2_rn(__expf(lrelu(a0.z + b0.z)), __expf(lrelu(a0.w + b0.w)));
        u.h2[2] = __floats2half2_rn(__expf(lrelu(a1v.x + b1v.x)), __expf(lrelu(a1v.y + b1v.y)));
        u.h2[3] = __floats2half2_rn(__expf(lrelu(a1v.z + b1v.z)), __expf(lrelu(a1v.w + b1v.w)));
        *reinterpret_cast<float4*>(&wc1[(size_t)slot * HEADS]) = u.f4;
    }
}

// ---- K6: layer-1 aggregation. 256 thr = 2 nodes x 128 lanes, 2 ch/lane.
__global__ __launch_bounds__(256) void k_agg1(
    const int* __restrict__ rowptr, const int* __restrict__ csr,
    const __half* __restrict__ h1h, const __half* __restrict__ wc1,
    const float* __restrict__ b1, __half* __restrict__ h1p)
{
    const int n = blockIdx.x * 2 + (threadIdx.x >> 7);
    const int t = threadIdx.x & 127;
    const int head = t >> 4;
    const int beg = rowptr[n], end = rowptr[n + 1];
    float ax = 0.f, ay = 0.f, accw = 0.f;
    int e = beg;
    for (; e + 3 < end; e += 4) {
        const int s0 = csr[e], s1 = csr[e + 1], s2 = csr[e + 2], s3 = csr[e + 3];
        const float w0 = __half2float(wc1[(size_t)(e + 0) * HEADS + head]);
        const float w1 = __half2float(wc1[(size_t)(e + 1) * HEADS + head]);
        const float w2 = __half2float(wc1[(size_t)(e + 2) * HEADS + head]);
        const float w3 = __half2float(wc1[(size_t)(e + 3) * HEADS + head]);
        const float2 f0 = __half22float2(*reinterpret_cast<const __half2*>(&h1h[(size_t)s0 * C1 + 2 * t]));
        const float2 f1 = __half22float2(*reinterpret_cast<const __half2*>(&h1h[(size_t)s1 * C1 + 2 * t]));
        const float2 f2 = __half22float2(*reinterpret_cast<const __half2*>(&h1h[(size_t)s2 * C1 + 2 * t]));
        const float2 f3 = __half22float2(*reinterpret_cast<const __half2*>(&h1h[(size_t)s3 * C1 + 2 * t]));
        accw += (w0 + w1) + (w2 + w3);
        ax = fmaf(w0, f0.x, ax); ay = fmaf(w0, f0.y, ay);
        ax = fmaf(w1, f1.x, ax); ay = fmaf(w1, f1.y, ay);
        ax = fmaf(w2, f2.x, ax); ay = fmaf(w2, f2.y, ay);
        ax = fmaf(w3, f3.x, ax); ay = fmaf(w3, f3.y, ay);
    }
    for (; e < end; e++) {
        const int s = csr[e];
        const float w = __half2float(wc1[(size_t)e * HEADS + head]);
        const float2 f = __half22float2(*reinterpret_cast<const __half2*>(&h1h[(size_t)s * C1 + 2 * t]));
        accw += w;
        ax = fmaf(w, f.x, ax); ay = fmaf(w, f.y, ay);
    }
    const float inv = 1.f / accw;
    float ox = ax * inv + b1[2 * t];
    float oy = ay * inv + b1[2 * t + 1];
    ox = (ox > 0.f) ? ox : (__expf(ox) - 1.f);
    oy = (oy > 0.f) ? oy : (__expf(oy) - 1.f);
    *reinterpret_cast<__half2*>(&h1p[(size_t)n * C1 + 2 * t]) = __floats2half2_rn(ox, oy);
}

// ---- K7: h2 = h1p @ W2 ; as2/ad2. One wave per 4 nodes.
__global__ __launch_bounds__(256) void k_gemm2(
    const __half* __restrict__ h1p, const float* __restrict__ W2,
    const float* __restrict__ a2s, const float* __restrict__ a2d,
    __half* __restrict__ h2h, float* __restrict__ as2, float* __restrict__ ad2)
{
    const int lane = threadIdx.x & 63;
    const int wid = (blockIdx.x * blockDim.x + threadIdx.x) >> 6;
    const int n0 = wid * 4;
    const int c = lane;
    const int cc = (c < NC) ? c : (NC - 1);
    float acc[4] = {0.f, 0.f, 0.f, 0.f};
    for (int k = 0; k < C1; k += 8) {
        float w[8];
#pragma unroll
        for (int j = 0; j < 8; j++) w[j] = W2[(k + j) * NC + cc];
#pragma unroll
        for (int r = 0; r < 4; r++) {
            union { float4 f4; __half2 h2[4]; } u;
            u.f4 = *reinterpret_cast<const float4*>(&h1p[(size_t)(n0 + r) * C1 + k]);
#pragma unroll
            for (int j = 0; j < 4; j++) {
                const float2 f = __half22float2(u.h2[j]);
                acc[r] = fmaf(f.x, w[2 * j], acc[r]);
                acc[r] = fmaf(f.y, w[2 * j + 1], acc[r]);
            }
        }
    }
    const float a_s = (c < NC) ? a2s[c] : 0.f;
    const float a_d = (c < NC) ? a2d[c] : 0.f;
#pragma unroll
    for (int j = 0; j < 4; j++) {
        const float v = acc[j];
        if (c < NC) h2h[(size_t)(n0 + j) * NC + c] = __float2half(v);
        float ps = (c < NC) ? v * a_s : 0.f;
        float pd = (c < NC) ? v * a_d : 0.f;
#pragma unroll
        for (int off = 32; off >= 1; off >>= 1) {
            ps += __shfl_xor(ps, off);
            pd += __shfl_xor(pd, off);
        }
        if (lane == 0) { as2[n0 + j] = ps; ad2[n0 + j] = pd; }
    }
}

// ---- K8: layer-2 aggregation + bias + log_softmax. One wave/node.
__global__ __launch_bounds__(256) void k_agg2(
    const int* __restrict__ rowptr, const int* __restrict__ csr,
    const __half* __restrict__ h2h, const float* __restrict__ as2,
    const float* __restrict__ ad2, const float* __restrict__ b2,
    float* __restrict__ out)
{
    const int lane = threadIdx.x & 63;
    const int n = (blockIdx.x * blockDim.x + threadIdx.x) >> 6;
    const int c = lane;
    const int cc = (c < NC) ? c : (NC - 1);
    const float adv = ad2[n];
    const int beg = rowptr[n], end = rowptr[n + 1];
    float acc = 0.f, accw = 0.f;
    int e = beg;
    for (; e + 3 < end; e += 4) {
        const int s0 = csr[e], s1 = csr[e + 1], s2 = csr[e + 2], s3 = csr[e + 3];
        const float w0 = __expf(lrelu(as2[s0] + adv));
        const float w1 = __expf(lrelu(as2[s1] + adv));
        const float w2 = __expf(lrelu(as2[s2] + adv));
        const float w3 = __expf(lrelu(as2[s3] + adv));
        const float g0 = __half2float(h2h[(size_t)s0 * NC + cc]);
        const float g1 = __half2float(h2h[(size_t)s1 * NC + cc]);
        const float g2 = __half2float(h2h[(size_t)s2 * NC + cc]);
        const float g3 = __half2float(h2h[(size_t)s3 * NC + cc]);
        accw += (w0 + w1) + (w2 + w3);
        acc = fmaf(w0, g0, acc);
        acc = fmaf(w1, g1, acc);
        acc = fmaf(w2, g2, acc);
        acc = fmaf(w3, g3, acc);
    }
    for (; e < end; e++) {
        const int s = csr[e];
        const float w = __expf(lrelu(as2[s] + adv));
        accw += w;
        acc = fmaf(w, __half2float(h2h[(size_t)s * NC + cc]), acc);
    }
    const float v = acc / accw + b2[cc];
    float m = (c < NC) ? v : -1e30f;
#pragma unroll
    for (int off = 32; off >= 1; off >>= 1) m = fmaxf(m, __shfl_xor(m, off));
    float S = (c < NC) ? __expf(v - m) : 0.f;
#pragma unroll
    for (int off = 32; off >= 1; off >>= 1) S += __shfl_xor(S, off);
    if (c < NC) out[(size_t)n * NC + c] = v - m - logf(S);
}

extern "C" void kernel_launch(void* const* d_in, const int* in_sizes, int n_in,
                              void* d_out, int out_size, void* d_ws, size_t ws_size,
                              hipStream_t stream)
{
    const float* x   = (const float*)d_in[0];
    const int*   ei  = (const int*)d_in[1];
    const float* W1  = (const float*)d_in[2];
    const float* a1s = (const float*)d_in[3];
    const float* a1d = (const float*)d_in[4];
    const float* b1  = (const float*)d_in[5];
    const float* W2  = (const float*)d_in[6];
    const float* a2s = (const float*)d_in[7];
    const float* a2d = (const float*)d_in[8];
    const float* b2  = (const float*)d_in[9];
    float* out = (float*)d_out;

    const int E  = in_sizes[1] / 2;
    const int ET = E + N;

    auto align64 = [](size_t v) { return (v + 63) & ~(size_t)63; };
    char* ws = (char*)d_ws;
    size_t off = 0;
    _Float16* xh  = (_Float16*)(ws + off); off = align64(off + (size_t)NPAD * F * 2);
    _Float16* w1sw = (_Float16*)(ws + off); off = align64(off + (size_t)4096 * 8 * 2);
    __half* h1h = (__half*)(ws + off); off = align64(off + (size_t)N * C1 * 2);
    __half* h1p = (__half*)(ws + off); off = align64(off + (size_t)N * C1 * 2);
    __half* h2h = (__half*)(ws + off); off = align64(off + (size_t)N * NC * 2);
    float* as1 = (float*)(ws + off); off = align64(off + (size_t)N * HEADS * 4);
    float* ad1 = (float*)(ws + off); off = align64(off + (size_t)N * HEADS * 4);
    float* as2 = (float*)(ws + off); off = align64(off + (size_t)N * 4);
    float* ad2 = (float*)(ws + off); off = align64(off + (size_t)N * 4);
    int* hist   = (int*)(ws + off); off = align64(off + (size_t)HM * 4);
    int* bsum   = (int*)(ws + off); off = align64(off + (size_t)NB * 4);
    int* buck   = (int*)(ws + off); off = align64(off + (size_t)ET * 4);
    int* rowptr = (int*)(ws + off); off = align64(off + (size_t)(N + 1) * 4);
    int* csr    = (int*)(ws + off); off = align64(off + (size_t)ET * 4);
    __half* wc1 = (__half*)(ws + off); off = align64(off + (size_t)ET * HEADS * 2);

    k_misc<<<PREPX_BLOCKS + PREPW_BLOCKS + HBLOCKS, 256, 0, stream>>>(
        x, xh, W1, w1sw, ei, E, hist);
    k_gemm1_mfma<<<313, 256, 0, stream>>>(xh, w1sw, a1s, a1d, h1h, as1, ad1);
    k_bsum<<<NB, 256, 0, stream>>>(hist, bsum);
    k_bscan<<<1, 256, 0, stream>>>(bsum);
    k_hscan<<<NB, 256, 0, stream>>>(hist, bsum);
    k_scatter<<<HBLOCKS, 256, 0, stream>>>(ei, E, hist, buck);
    k_bucket<<<NB, 256, 0, stream>>>(hist, buck, ET, as1, ad1, csr, rowptr, wc1);
    k_agg1<<<N / 2, 256, 0, stream>>>(rowptr, csr, h1h, wc1, b1, h1p);
    k_gemm2<<<1250, 256, 0, stream>>>(h1p, W2, a2s, a2d, h2h, as2, ad2);
    k_agg2<<<5000, 256, 0, stream>>>(rowptr, csr, h2h, as2, ad2, b2, out);
}

// Round 13
// 226.316 us; speedup vs baseline: 1.0732x; 1.0732x over previous
//
#include <hip/hip_runtime.h>
#include <hip/hip_fp16.h>
#include <math.h>

#define N 20000
#define NPAD 20032
#define F 128
#define C1 256   // HEADS*HIDDEN
#define HEADS 8
#define HID 32
#define NC 40
#define NEG 0.2f

#define BSHIFT 7
#define NB 157        // buckets of 128 nodes
#define HBLOCKS 256
#define HM (NB * HBLOCKS)

#define PREPX_BLOCKS 2504
#define PREPW_BLOCKS 16

typedef _Float16 half8 __attribute__((ext_vector_type(8)));
typedef _Float16 half4v __attribute__((ext_vector_type(4)));
typedef float f32x4 __attribute__((ext_vector_type(4)));

__device__ __forceinline__ int edge_stride(const int* ei) {
    return (ei[1] == 0 && ei[3] == 0 && ei[5] == 0 && ei[7] == 0 && ei[9] == 0) ? 2 : 1;
}

__device__ __forceinline__ float lrelu(float v) { return v > 0.f ? v : NEG * v; }

// ---- K0: fused prep_x, prep_w, bucket histogram (LDS atomics only)
__global__ __launch_bounds__(256) void k_misc(
    const float* __restrict__ x, _Float16* __restrict__ xh,
    const float* __restrict__ W1, _Float16* __restrict__ w1sw,
    const int* __restrict__ ei, int E, int* __restrict__ hist)
{
    const int b = blockIdx.x;
    const int tid = threadIdx.x;
    if (b < PREPX_BLOCKS) {
        const int idx = (b * 256 + tid) * 4;
        half4v o;
        if (idx < N * F) {
            const float4 v = *reinterpret_cast<const float4*>(&x[idx]);
            o[0] = (_Float16)v.x; o[1] = (_Float16)v.y; o[2] = (_Float16)v.z; o[3] = (_Float16)v.w;
        } else {
            o[0] = (_Float16)0.f; o[1] = (_Float16)0.f; o[2] = (_Float16)0.f; o[3] = (_Float16)0.f;
        }
        *reinterpret_cast<half4v*>(&xh[idx]) = o;
    } else if (b < PREPX_BLOCKS + PREPW_BLOCKS) {
        const int slot = (b - PREPX_BLOCKS) * 256 + tid;
        const int lane = slot & 63;
        const int tile = slot >> 6;
        const int nt = tile & 15, ks = tile >> 4;
        const int n = nt * 16 + (lane & 15);
        const int k0 = ks * 32 + (lane >> 4) * 8;
        half8 tmp;
#pragma unroll
        for (int j = 0; j < 8; j++) tmp[j] = (_Float16)W1[(k0 + j) * C1 + n];
        *reinterpret_cast<half8*>(&w1sw[(size_t)slot * 8]) = tmp;
    } else {
        __shared__ int hcnt[NB];
        const int hb = b - PREPX_BLOCKS - PREPW_BLOCKS;
        if (tid < NB) hcnt[tid] = 0;
        __syncthreads();
        const int ET = E + N;
        const int per = (ET + HBLOCKS - 1) / HBLOCKS;
        const int lo = hb * per;
        const int hi = (lo + per < ET) ? (lo + per) : ET;
        const int st = edge_stride(ei);
        for (int i = lo + tid; i < hi; i += 256) {
            const int d = (i < E) ? ei[(size_t)st * (E + i)] : (i - E);
            atomicAdd(&hcnt[d >> BSHIFT], 1);
        }
        __syncthreads();
        if (tid < NB) hist[tid * HBLOCKS + hb] = hcnt[tid];
    }
}

// ---- K1: h1 = x @ W1 via MFMA; fused as1/ad1 projections.
__global__ __launch_bounds__(256) void k_gemm1_mfma(
    const _Float16* __restrict__ xh, const _Float16* __restrict__ w1sw,
    const float* __restrict__ a1s, const float* __restrict__ a1d,
    __half* __restrict__ h1h, float* __restrict__ as1, float* __restrict__ ad1)
{
    const int lane = threadIdx.x & 63;
    const int wid = (blockIdx.x * 256 + threadIdx.x) >> 6;
    const int m0 = wid * 16;
    const int g = lane >> 4, lm = lane & 15;
    half8 a[4];
    const size_t arow = (size_t)(m0 + lm) * F;
#pragma unroll
    for (int ks = 0; ks < 4; ks++)
        a[ks] = *reinterpret_cast<const half8*>(&xh[arow + ks * 32 + g * 8]);
    const int rbase = m0 + g * 4;
    float ps[4] = {0.f, 0.f, 0.f, 0.f}, pd[4] = {0.f, 0.f, 0.f, 0.f};
#pragma unroll
    for (int nt = 0; nt < 16; nt++) {
        f32x4 acc = {0.f, 0.f, 0.f, 0.f};
#pragma unroll
        for (int ks = 0; ks < 4; ks++) {
            const half8 bfr = *reinterpret_cast<const half8*>(&w1sw[(size_t)((ks * 16 + nt) * 64 + lane) * 8]);
            acc = __builtin_amdgcn_mfma_f32_16x16x32_f16(a[ks], bfr, acc, 0, 0, 0);
        }
        const int col = nt * 16 + lm;
        const float av = a1s[col], dv = a1d[col];
#pragma unroll
        for (int r = 0; r < 4; r++) {
            const int row = rbase + r;
            if (row < N) h1h[(size_t)row * C1 + col] = __float2half((float)acc[r]);
            ps[r] = fmaf((float)acc[r], av, ps[r]);
            pd[r] = fmaf((float)acc[r], dv, pd[r]);
        }
        if (nt & 1) {
#pragma unroll
            for (int off = 1; off <= 8; off <<= 1) {
#pragma unroll
                for (int r = 0; r < 4; r++) {
                    ps[r] += __shfl_xor(ps[r], off);
                    pd[r] += __shfl_xor(pd[r], off);
                }
            }
            if (lm == 0) {
                const int head = nt >> 1;
#pragma unroll
                for (int r = 0; r < 4; r++) {
                    const int row = rbase + r;
                    if (row < N) {
                        as1[row * HEADS + head] = ps[r];
                        ad1[row * HEADS + head] = pd[r];
                    }
                }
            }
#pragma unroll
            for (int r = 0; r < 4; r++) { ps[r] = 0.f; pd[r] = 0.f; }
        }
    }
}

// ---- K2a: per-bucket sums (157 blocks x 256 thr)
__global__ __launch_bounds__(256) void k_bsum(const int* __restrict__ hist,
                                              int* __restrict__ bsum)
{
    __shared__ int wsum[4];
    const int b = blockIdx.x;
    const int tid = threadIdx.x;
    const int lane = tid & 63, wid = tid >> 6;
    int v = hist[b * HBLOCKS + tid];
#pragma unroll
    for (int off = 32; off >= 1; off >>= 1) v += __shfl_xor(v, off);
    if (lane == 0) wsum[wid] = v;
    __syncthreads();
    if (tid == 0) bsum[b] = wsum[0] + wsum[1] + wsum[2] + wsum[3];
}

// ---- K2b: exclusive scan of bsum[157] in place. One block.
__global__ __launch_bounds__(256) void k_bscan(int* __restrict__ bsum)
{
    __shared__ int wbase[4];
    const int t = threadIdx.x;
    const int lane = t & 63, wid = t >> 6;
    const int vin = (t < NB) ? bsum[t] : 0;
    int v = vin;
#pragma unroll
    for (int off = 1; off < 64; off <<= 1) {
        const int u = __shfl_up(v, off, 64);
        if (lane >= off) v += u;
    }
    if (lane == 63) wbase[wid] = v;
    __syncthreads();
    if (t < 64) {
        int w = (lane < 4) ? wbase[lane] : 0;
        const int orig = w;
#pragma unroll
        for (int off = 1; off < 4; off <<= 1) {
            const int u = __shfl_up(w, off, 64);
            if (lane >= off) w += u;
        }
        if (lane < 4) wbase[lane] = w - orig;
    }
    __syncthreads();
    if (t < NB) bsum[t] = wbase[wid] + v - vin;   // exclusive
}

// ---- K2c: per-bucket exclusive scan + bucket base -> hist in place.
__global__ __launch_bounds__(256) void k_hscan(int* __restrict__ hist,
                                               const int* __restrict__ bsum)
{
    __shared__ int wbase[4];
    const int b = blockIdx.x;
    const int tid = threadIdx.x;
    const int lane = tid & 63, wid = tid >> 6;
    const int vin = hist[b * HBLOCKS + tid];
    int v = vin;
#pragma unroll
    for (int off = 1; off < 64; off <<= 1) {
        const int u = __shfl_up(v, off, 64);
        if (lane >= off) v += u;
    }
    if (lane == 63) wbase[wid] = v;
    __syncthreads();
    if (tid < 64) {
        int w = (lane < 4) ? wbase[lane] : 0;
        const int orig = w;
#pragma unroll
        for (int off = 1; off < 4; off <<= 1) {
            const int u = __shfl_up(w, off, 64);
            if (lane >= off) w += u;
        }
        if (lane < 4) wbase[lane] = w - orig;
    }
    __syncthreads();
    hist[b * HBLOCKS + tid] = bsum[b] + wbase[wid] + v - vin;
}

// ---- K3: scatter edges into coarse buckets. LDS cursors only.
__global__ __launch_bounds__(256) void k_scatter(
    const int* __restrict__ ei, int E, const int* __restrict__ hist,
    int* __restrict__ buck)
{
    __shared__ int cur[NB];
    const int hb = blockIdx.x;
    const int tid = threadIdx.x;
    if (tid < NB) cur[tid] = hist[tid * HBLOCKS + hb];
    __syncthreads();
    const int ET = E + N;
    const int per = (ET + HBLOCKS - 1) / HBLOCKS;
    const int lo = hb * per;
    const int hi = (lo + per < ET) ? (lo + per) : ET;
    const int st = edge_stride(ei);
    for (int i = lo + tid; i < hi; i += 256) {
        int s, d;
        if (i < E) { s = ei[(size_t)st * i]; d = ei[(size_t)st * (E + i)]; }
        else       { s = i - E; d = i - E; }
        const int slot = atomicAdd(&cur[d >> BSHIFT], 1);
        buck[slot] = ((d & 127) << 16) | s;
    }
}

// ---- K4: per-bucket counting sort -> csr + rowptr.
__global__ __launch_bounds__(256) void k_bucket(
    const int* __restrict__ hist, const int* __restrict__ buck, int ET,
    int* __restrict__ csr, int* __restrict__ rowptr)
{
    __shared__ int cnt[128];
    __shared__ int pfx[128];
    const int b = blockIdx.x;
    const int tid = threadIdx.x;
    const int start = hist[b * HBLOCKS];
    const int end = (b == NB - 1) ? ET : hist[(b + 1) * HBLOCKS];
    if (tid < 128) cnt[tid] = 0;
    __syncthreads();
    for (int i = start + tid; i < end; i += 256)
        atomicAdd(&cnt[buck[i] >> 16], 1);
    __syncthreads();
    if (tid < 128) pfx[tid] = cnt[tid];
    __syncthreads();
    for (int off = 1; off < 128; off <<= 1) {
        int u = 0;
        if (tid < 128 && tid >= off) u = pfx[tid - off];
        __syncthreads();
        if (tid < 128) pfx[tid] += u;
        __syncthreads();
    }
    if (tid < 128) {
        const int node = b * 128 + tid;
        const int ebase = start + pfx[tid] - cnt[tid];
        if (node < N) rowptr[node] = ebase;
        cnt[tid] = ebase;
    }
    if (b == NB - 1 && tid == 0) rowptr[N] = ET;
    __syncthreads();
    for (int i = start + tid; i < end; i += 256) {
        const int val = buck[i];
        const int slot = atomicAdd(&cnt[val >> 16], 1);
        csr[slot] = val & 0xFFFF;
    }
}

// ---- K5: layer-1 edge weights in CSR order (16B/edge). One wave/node.
__global__ __launch_bounds__(256) void k_w1(
    const int* __restrict__ rowptr, const int* __restrict__ csr,
    const float* __restrict__ as1, const float* __restrict__ ad1,
    __half* __restrict__ wc1)
{
    const int lane = threadIdx.x & 63;
    const int n = (blockIdx.x * 256 + threadIdx.x) >> 6;
    const int beg = rowptr[n], end = rowptr[n + 1];
    const float4 b0 = *reinterpret_cast<const float4*>(&ad1[n * HEADS]);
    const float4 b1v = *reinterpret_cast<const float4*>(&ad1[n * HEADS + 4]);
    for (int e = beg + lane; e < end; e += 64) {
        const int s = csr[e];
        const float4 a0 = *reinterpret_cast<const float4*>(&as1[s * HEADS]);
        const float4 a1v = *reinterpret_cast<const float4*>(&as1[s * HEADS + 4]);
        union { float4 f4; __half2 h2[4]; } u;
        u.h2[0] = __floats2half2_rn(__expf(lrelu(a0.x + b0.x)), __expf(lrelu(a0.y + b0.y)));
        u.h2[1] = __floats2half2_rn(__expf(lrelu(a0.z + b0.z)), __expf(lrelu(a0.w + b0.w)));
        u.h2[2] = __floats2half2_rn(__expf(lrelu(a1v.x + b1v.x)), __expf(lrelu(a1v.y + b1v.y)));
        u.h2[3] = __floats2half2_rn(__expf(lrelu(a1v.z + b1v.z)), __expf(lrelu(a1v.w + b1v.w)));
        *reinterpret_cast<float4*>(&wc1[(size_t)e * HEADS]) = u.f4;
    }
}

// ---- K6: layer-1 aggregation. 128 thr/node, 2 ch/thread, unroll 8.
__global__ __launch_bounds__(128) void k_agg1(
    const int* __restrict__ rowptr, const int* __restrict__ csr,
    const __half* __restrict__ h1h, const __half* __restrict__ wc1,
    const float* __restrict__ b1, __half* __restrict__ h1p)
{
    const int n = blockIdx.x;
    const int t = threadIdx.x;
    const int head = t >> 4;
    const int beg = rowptr[n], end = rowptr[n + 1];
    float ax = 0.f, ay = 0.f, accw = 0.f;
    int e = beg;
    for (; e + 7 < end; e += 8) {
        int s[8];
        float w[8];
        float2 f[8];
#pragma unroll
        for (int j = 0; j < 8; j++) s[j] = csr[e + j];
#pragma unroll
        for (int j = 0; j < 8; j++) w[j] = __half2float(wc1[(size_t)(e + j) * HEADS + head]);
#pragma unroll
        for (int j = 0; j < 8; j++)
            f[j] = __half22float2(*reinterpret_cast<const __half2*>(&h1h[(size_t)s[j] * C1 + 2 * t]));
#pragma unroll
        for (int j = 0; j < 8; j++) {
            accw += w[j];
            ax = fmaf(w[j], f[j].x, ax);
            ay = fmaf(w[j], f[j].y, ay);
        }
    }
    for (; e + 3 < end; e += 4) {
        const int s0 = csr[e], s1 = csr[e + 1], s2 = csr[e + 2], s3 = csr[e + 3];
        const float w0 = __half2float(wc1[(size_t)(e + 0) * HEADS + head]);
        const float w1 = __half2float(wc1[(size_t)(e + 1) * HEADS + head]);
        const float w2 = __half2float(wc1[(size_t)(e + 2) * HEADS + head]);
        const float w3 = __half2float(wc1[(size_t)(e + 3) * HEADS + head]);
        const float2 f0 = __half22float2(*reinterpret_cast<const __half2*>(&h1h[(size_t)s0 * C1 + 2 * t]));
        const float2 f1 = __half22float2(*reinterpret_cast<const __half2*>(&h1h[(size_t)s1 * C1 + 2 * t]));
        const float2 f2 = __half22float2(*reinterpret_cast<const __half2*>(&h1h[(size_t)s2 * C1 + 2 * t]));
        const float2 f3 = __half22float2(*reinterpret_cast<const __half2*>(&h1h[(size_t)s3 * C1 + 2 * t]));
        accw += (w0 + w1) + (w2 + w3);
        ax = fmaf(w0, f0.x, ax); ay = fmaf(w0, f0.y, ay);
        ax = fmaf(w1, f1.x, ax); ay = fmaf(w1, f1.y, ay);
        ax = fmaf(w2, f2.x, ax); ay = fmaf(w2, f2.y, ay);
        ax = fmaf(w3, f3.x, ax); ay = fmaf(w3, f3.y, ay);
    }
    for (; e < end; e++) {
        const int s = csr[e];
        const float w = __half2float(wc1[(size_t)e * HEADS + head]);
        const float2 f = __half22float2(*reinterpret_cast<const __half2*>(&h1h[(size_t)s * C1 + 2 * t]));
        accw += w;
        ax = fmaf(w, f.x, ax); ay = fmaf(w, f.y, ay);
    }
    const float inv = 1.f / accw;
    float ox = ax * inv + b1[2 * t];
    float oy = ay * inv + b1[2 * t + 1];
    ox = (ox > 0.f) ? ox : (__expf(ox) - 1.f);
    oy = (oy > 0.f) ? oy : (__expf(oy) - 1.f);
    *reinterpret_cast<__half2*>(&h1p[(size_t)n * C1 + 2 * t]) = __floats2half2_rn(ox, oy);
}

// ---- K7: h2 = h1p @ W2 ; as2/ad2. One wave per 4 nodes.
__global__ __launch_bounds__(256) void k_gemm2(
    const __half* __restrict__ h1p, const float* __restrict__ W2,
    const float* __restrict__ a2s, const float* __restrict__ a2d,
    __half* __restrict__ h2h, float* __restrict__ as2, float* __restrict__ ad2)
{
    const int lane = threadIdx.x & 63;
    const int wid = (blockIdx.x * blockDim.x + threadIdx.x) >> 6;
    const int n0 = wid * 4;
    const int c = lane;
    const int cc = (c < NC) ? c : (NC - 1);
    float acc[4] = {0.f, 0.f, 0.f, 0.f};
    for (int k = 0; k < C1; k += 8) {
        float w[8];
#pragma unroll
        for (int j = 0; j < 8; j++) w[j] = W2[(k + j) * NC + cc];
#pragma unroll
        for (int r = 0; r < 4; r++) {
            union { float4 f4; __half2 h2[4]; } u;
            u.f4 = *reinterpret_cast<const float4*>(&h1p[(size_t)(n0 + r) * C1 + k]);
#pragma unroll
            for (int j = 0; j < 4; j++) {
                const float2 f = __half22float2(u.h2[j]);
                acc[r] = fmaf(f.x, w[2 * j], acc[r]);
                acc[r] = fmaf(f.y, w[2 * j + 1], acc[r]);
            }
        }
    }
    const float a_s = (c < NC) ? a2s[c] : 0.f;
    const float a_d = (c < NC) ? a2d[c] : 0.f;
#pragma unroll
    for (int j = 0; j < 4; j++) {
        const float v = acc[j];
        if (c < NC) h2h[(size_t)(n0 + j) * NC + c] = __float2half(v);
        float ps = (c < NC) ? v * a_s : 0.f;
        float pd = (c < NC) ? v * a_d : 0.f;
#pragma unroll
        for (int off = 32; off >= 1; off >>= 1) {
            ps += __shfl_xor(ps, off);
            pd += __shfl_xor(pd, off);
        }
        if (lane == 0) { as2[n0 + j] = ps; ad2[n0 + j] = pd; }
    }
}

// ---- K8: layer-2 aggregation + bias + log_softmax. One wave/node.
__global__ __launch_bounds__(256) void k_agg2(
    const int* __restrict__ rowptr, const int* __restrict__ csr,
    const __half* __restrict__ h2h, const float* __restrict__ as2,
    const float* __restrict__ ad2, const float* __restrict__ b2,
    float* __restrict__ out)
{
    const int lane = threadIdx.x & 63;
    const int n = (blockIdx.x * blockDim.x + threadIdx.x) >> 6;
    const int c = lane;
    const int cc = (c < NC) ? c : (NC - 1);
    const float adv = ad2[n];
    const int beg = rowptr[n], end = rowptr[n + 1];
    float acc = 0.f, accw = 0.f;
    int e = beg;
    for (; e + 3 < end; e += 4) {
        const int s0 = csr[e], s1 = csr[e + 1], s2 = csr[e + 2], s3 = csr[e + 3];
        const float w0 = __expf(lrelu(as2[s0] + adv));
        const float w1 = __expf(lrelu(as2[s1] + adv));
        const float w2 = __expf(lrelu(as2[s2] + adv));
        const float w3 = __expf(lrelu(as2[s3] + adv));
        const float g0 = __half2float(h2h[(size_t)s0 * NC + cc]);
        const float g1 = __half2float(h2h[(size_t)s1 * NC + cc]);
        const float g2 = __half2float(h2h[(size_t)s2 * NC + cc]);
        const float g3 = __half2float(h2h[(size_t)s3 * NC + cc]);
        accw += (w0 + w1) + (w2 + w3);
        acc = fmaf(w0, g0, acc);
        acc = fmaf(w1, g1, acc);
        acc = fmaf(w2, g2, acc);
        acc = fmaf(w3, g3, acc);
    }
    for (; e < end; e++) {
        const int s = csr[e];
        const float w = __expf(lrelu(as2[s] + adv));
        accw += w;
        acc = fmaf(w, __half2float(h2h[(size_t)s * NC + cc]), acc);
    }
    const float v = acc / accw + b2[cc];
    float m = (c < NC) ? v : -1e30f;
#pragma unroll
    for (int off = 32; off >= 1; off >>= 1) m = fmaxf(m, __shfl_xor(m, off));
    float S = (c < NC) ? __expf(v - m) : 0.f;
#pragma unroll
    for (int off = 32; off >= 1; off >>= 1) S += __shfl_xor(S, off);
    if (c < NC) out[(size_t)n * NC + c] = v - m - logf(S);
}

extern "C" void kernel_launch(void* const* d_in, const int* in_sizes, int n_in,
                              void* d_out, int out_size, void* d_ws, size_t ws_size,
                              hipStream_t stream)
{
    const float* x   = (const float*)d_in[0];
    const int*   ei  = (const int*)d_in[1];
    const float* W1  = (const float*)d_in[2];
    const float* a1s = (const float*)d_in[3];
    const float* a1d = (const float*)d_in[4];
    const float* b1  = (const float*)d_in[5];
    const float* W2  = (const float*)d_in[6];
    const float* a2s = (const float*)d_in[7];
    const float* a2d = (const float*)d_in[8];
    const float* b2  = (const float*)d_in[9];
    float* out = (float*)d_out;

    const int E  = in_sizes[1] / 2;
    const int ET = E + N;

    auto align64 = [](size_t v) { return (v + 63) & ~(size_t)63; };
    char* ws = (char*)d_ws;
    size_t off = 0;
    _Float16* xh  = (_Float16*)(ws + off); off = align64(off + (size_t)NPAD * F * 2);
    _Float16* w1sw = (_Float16*)(ws + off); off = align64(off + (size_t)4096 * 8 * 2);
    __half* h1h = (__half*)(ws + off); off = align64(off + (size_t)N * C1 * 2);
    __half* h1p = (__half*)(ws + off); off = align64(off + (size_t)N * C1 * 2);
    __half* h2h = (__half*)(ws + off); off = align64(off + (size_t)N * NC * 2);
    float* as1 = (float*)(ws + off); off = align64(off + (size_t)N * HEADS * 4);
    float* ad1 = (float*)(ws + off); off = align64(off + (size_t)N * HEADS * 4);
    float* as2 = (float*)(ws + off); off = align64(off + (size_t)N * 4);
    float* ad2 = (float*)(ws + off); off = align64(off + (size_t)N * 4);
    int* hist   = (int*)(ws + off); off = align64(off + (size_t)HM * 4);
    int* bsum   = (int*)(ws + off); off = align64(off + (size_t)NB * 4);
    int* buck   = (int*)(ws + off); off = align64(off + (size_t)ET * 4);
    int* rowptr = (int*)(ws + off); off = align64(off + (size_t)(N + 1) * 4);
    int* csr    = (int*)(ws + off); off = align64(off + (size_t)ET * 4);
    __half* wc1 = (__half*)(ws + off); off = align64(off + (size_t)ET * HEADS * 2);

    k_misc<<<PREPX_BLOCKS + PREPW_BLOCKS + HBLOCKS, 256, 0, stream>>>(
        x, xh, W1, w1sw, ei, E, hist);
    k_gemm1_mfma<<<313, 256, 0, stream>>>(xh, w1sw, a1s, a1d, h1h, as1, ad1);
    k_bsum<<<NB, 256, 0, stream>>>(hist, bsum);
    k_bscan<<<1, 256, 0, stream>>>(bsum);
    k_hscan<<<NB, 256, 0, stream>>>(hist, bsum);
    k_scatter<<<HBLOCKS, 256, 0, stream>>>(ei, E, hist, buck);
    k_bucket<<<NB, 256, 0, stream>>>(hist, buck, ET, csr, rowptr);
    k_w1<<<5000, 256, 0, stream>>>(rowptr, csr, as1, ad1, wc1);
    k_agg1<<<N, 128, 0, stream>>>(rowptr, csr, h1h, wc1, b1, h1p);
    k_gemm2<<<1250, 256, 0, stream>>>(h1p, W2, a2s, a2d, h2h, as2, ad2);
    k_agg2<<<5000, 256, 0, stream>>>(rowptr, csr, h2h, as2, ad2, b2, out);
}

// Round 14
// 222.158 us; speedup vs baseline: 1.0932x; 1.0187x over previous
//
#include <hip/hip_runtime.h>
#include <hip/hip_fp16.h>
#include <math.h>

#define N 20000
#define F 128
#define C1 256   // HEADS*HIDDEN
#define HEADS 8
#define HID 32
#define NC 40
#define NEG 0.2f

#define BSHIFT 7
#define NB 157        // buckets of 128 nodes
#define HBLOCKS 256
#define HM (NB * HBLOCKS)

#define PREPW_BLOCKS 16

typedef _Float16 half8 __attribute__((ext_vector_type(8)));
typedef float f32x4 __attribute__((ext_vector_type(4)));

__device__ __forceinline__ int edge_stride(const int* ei) {
    return (ei[1] == 0 && ei[3] == 0 && ei[5] == 0 && ei[7] == 0 && ei[9] == 0) ? 2 : 1;
}

__device__ __forceinline__ float lrelu(float v) { return v > 0.f ? v : NEG * v; }

// ---- K0: fused prep_w (W1 swizzle) + bucket histogram (LDS atomics only)
__global__ __launch_bounds__(256) void k_misc(
    const float* __restrict__ W1, _Float16* __restrict__ w1sw,
    const int* __restrict__ ei, int E, int* __restrict__ hist)
{
    const int b = blockIdx.x;
    const int tid = threadIdx.x;
    if (b < PREPW_BLOCKS) {
        const int slot = b * 256 + tid;
        const int lane = slot & 63;
        const int tile = slot >> 6;
        const int nt = tile & 15, ks = tile >> 4;
        const int n = nt * 16 + (lane & 15);
        const int k0 = ks * 32 + (lane >> 4) * 8;
        half8 tmp;
#pragma unroll
        for (int j = 0; j < 8; j++) tmp[j] = (_Float16)W1[(k0 + j) * C1 + n];
        *reinterpret_cast<half8*>(&w1sw[(size_t)slot * 8]) = tmp;
    } else {
        __shared__ int hcnt[NB];
        const int hb = b - PREPW_BLOCKS;
        if (tid < NB) hcnt[tid] = 0;
        __syncthreads();
        const int ET = E + N;
        const int per = (ET + HBLOCKS - 1) / HBLOCKS;
        const int lo = hb * per;
        const int hi = (lo + per < ET) ? (lo + per) : ET;
        const int st = edge_stride(ei);
        for (int i = lo + tid; i < hi; i += 256) {
            const int d = (i < E) ? ei[(size_t)st * (E + i)] : (i - E);
            atomicAdd(&hcnt[d >> BSHIFT], 1);
        }
        __syncthreads();
        if (tid < NB) hist[tid * HBLOCKS + hb] = hcnt[tid];
    }
}

// ---- K1: h1 = x @ W1 via MFMA (x read fp32, converted inline); fused projections.
__global__ __launch_bounds__(256) void k_gemm1_mfma(
    const float* __restrict__ x, const _Float16* __restrict__ w1sw,
    const float* __restrict__ a1s, const float* __restrict__ a1d,
    __half* __restrict__ h1h, float* __restrict__ as1, float* __restrict__ ad1)
{
    const int lane = threadIdx.x & 63;
    const int wid = (blockIdx.x * 256 + threadIdx.x) >> 6;
    const int m0 = wid * 16;
    const int g = lane >> 4, lm = lane & 15;
    const int arow = m0 + lm;
    half8 a[4];
    if (arow < N) {
        const float* xr = x + (size_t)arow * F;
#pragma unroll
        for (int ks = 0; ks < 4; ks++) {
            const float4 v0 = *reinterpret_cast<const float4*>(&xr[ks * 32 + g * 8]);
            const float4 v1 = *reinterpret_cast<const float4*>(&xr[ks * 32 + g * 8 + 4]);
            half8 t;
            t[0] = (_Float16)v0.x; t[1] = (_Float16)v0.y; t[2] = (_Float16)v0.z; t[3] = (_Float16)v0.w;
            t[4] = (_Float16)v1.x; t[5] = (_Float16)v1.y; t[6] = (_Float16)v1.z; t[7] = (_Float16)v1.w;
            a[ks] = t;
        }
    } else {
#pragma unroll
        for (int ks = 0; ks < 4; ks++) {
            half8 t;
#pragma unroll
            for (int j = 0; j < 8; j++) t[j] = (_Float16)0.f;
            a[ks] = t;
        }
    }
    const int rbase = m0 + g * 4;
    float ps[4] = {0.f, 0.f, 0.f, 0.f}, pd[4] = {0.f, 0.f, 0.f, 0.f};
#pragma unroll
    for (int nt = 0; nt < 16; nt++) {
        f32x4 acc = {0.f, 0.f, 0.f, 0.f};
#pragma unroll
        for (int ks = 0; ks < 4; ks++) {
            const half8 bfr = *reinterpret_cast<const half8*>(&w1sw[(size_t)((ks * 16 + nt) * 64 + lane) * 8]);
            acc = __builtin_amdgcn_mfma_f32_16x16x32_f16(a[ks], bfr, acc, 0, 0, 0);
        }
        const int col = nt * 16 + lm;
        const float av = a1s[col], dv = a1d[col];
#pragma unroll
        for (int r = 0; r < 4; r++) {
            const int row = rbase + r;
            if (row < N) h1h[(size_t)row * C1 + col] = __float2half((float)acc[r]);
            ps[r] = fmaf((float)acc[r], av, ps[r]);
            pd[r] = fmaf((float)acc[r], dv, pd[r]);
        }
        if (nt & 1) {
#pragma unroll
            for (int off = 1; off <= 8; off <<= 1) {
#pragma unroll
                for (int r = 0; r < 4; r++) {
                    ps[r] += __shfl_xor(ps[r], off);
                    pd[r] += __shfl_xor(pd[r], off);
                }
            }
            if (lm == 0) {
                const int head = nt >> 1;
#pragma unroll
                for (int r = 0; r < 4; r++) {
                    const int row = rbase + r;
                    if (row < N) {
                        as1[row * HEADS + head] = ps[r];
                        ad1[row * HEADS + head] = pd[r];
                    }
                }
            }
#pragma unroll
            for (int r = 0; r < 4; r++) { ps[r] = 0.f; pd[r] = 0.f; }
        }
    }
}

// ---- K2a: per-bucket sums (157 blocks x 256 thr)
__global__ __launch_bounds__(256) void k_bsum(const int* __restrict__ hist,
                                              int* __restrict__ bsum)
{
    __shared__ int wsum[4];
    const int b = blockIdx.x;
    const int tid = threadIdx.x;
    const int lane = tid & 63, wid = tid >> 6;
    int v = hist[b * HBLOCKS + tid];
#pragma unroll
    for (int off = 32; off >= 1; off >>= 1) v += __shfl_xor(v, off);
    if (lane == 0) wsum[wid] = v;
    __syncthreads();
    if (tid == 0) bsum[b] = wsum[0] + wsum[1] + wsum[2] + wsum[3];
}

// ---- K2b: exclusive scan of bsum[157] in place. One block.
__global__ __launch_bounds__(256) void k_bscan(int* __restrict__ bsum)
{
    __shared__ int wbase[4];
    const int t = threadIdx.x;
    const int lane = t & 63, wid = t >> 6;
    const int vin = (t < NB) ? bsum[t] : 0;
    int v = vin;
#pragma unroll
    for (int off = 1; off < 64; off <<= 1) {
        const int u = __shfl_up(v, off, 64);
        if (lane >= off) v += u;
    }
    if (lane == 63) wbase[wid] = v;
    __syncthreads();
    if (t < 64) {
        int w = (lane < 4) ? wbase[lane] : 0;
        const int orig = w;
#pragma unroll
        for (int off = 1; off < 4; off <<= 1) {
            const int u = __shfl_up(w, off, 64);
            if (lane >= off) w += u;
        }
        if (lane < 4) wbase[lane] = w - orig;
    }
    __syncthreads();
    if (t < NB) bsum[t] = wbase[wid] + v - vin;   // exclusive
}

// ---- K2c: per-bucket exclusive scan + bucket base -> hist in place.
__global__ __launch_bounds__(256) void k_hscan(int* __restrict__ hist,
                                               const int* __restrict__ bsum)
{
    __shared__ int wbase[4];
    const int b = blockIdx.x;
    const int tid = threadIdx.x;
    const int lane = tid & 63, wid = tid >> 6;
    const int vin = hist[b * HBLOCKS + tid];
    int v = vin;
#pragma unroll
    for (int off = 1; off < 64; off <<= 1) {
        const int u = __shfl_up(v, off, 64);
        if (lane >= off) v += u;
    }
    if (lane == 63) wbase[wid] = v;
    __syncthreads();
    if (tid < 64) {
        int w = (lane < 4) ? wbase[lane] : 0;
        const int orig = w;
#pragma unroll
        for (int off = 1; off < 4; off <<= 1) {
            const int u = __shfl_up(w, off, 64);
            if (lane >= off) w += u;
        }
        if (lane < 4) wbase[lane] = w - orig;
    }
    __syncthreads();
    hist[b * HBLOCKS + tid] = bsum[b] + wbase[wid] + v - vin;
}

// ---- K3: scatter edges into coarse buckets. LDS cursors only.
__global__ __launch_bounds__(256) void k_scatter(
    const int* __restrict__ ei, int E, const int* __restrict__ hist,
    int* __restrict__ buck)
{
    __shared__ int cur[NB];
    const int hb = blockIdx.x;
    const int tid = threadIdx.x;
    if (tid < NB) cur[tid] = hist[tid * HBLOCKS + hb];
    __syncthreads();
    const int ET = E + N;
    const int per = (ET + HBLOCKS - 1) / HBLOCKS;
    const int lo = hb * per;
    const int hi = (lo + per < ET) ? (lo + per) : ET;
    const int st = edge_stride(ei);
    for (int i = lo + tid; i < hi; i += 256) {
        int s, d;
        if (i < E) { s = ei[(size_t)st * i]; d = ei[(size_t)st * (E + i)]; }
        else       { s = i - E; d = i - E; }
        const int slot = atomicAdd(&cur[d >> BSHIFT], 1);
        buck[slot] = ((d & 127) << 16) | s;
    }
}

// ---- K4: per-bucket counting sort -> csr + rowptr.
__global__ __launch_bounds__(256) void k_bucket(
    const int* __restrict__ hist, const int* __restrict__ buck, int ET,
    int* __restrict__ csr, int* __restrict__ rowptr)
{
    __shared__ int cnt[128];
    __shared__ int pfx[128];
    const int b = blockIdx.x;
    const int tid = threadIdx.x;
    const int start = hist[b * HBLOCKS];
    const int end = (b == NB - 1) ? ET : hist[(b + 1) * HBLOCKS];
    if (tid < 128) cnt[tid] = 0;
    __syncthreads();
    for (int i = start + tid; i < end; i += 256)
        atomicAdd(&cnt[buck[i] >> 16], 1);
    __syncthreads();
    if (tid < 128) pfx[tid] = cnt[tid];
    __syncthreads();
    for (int off = 1; off < 128; off <<= 1) {
        int u = 0;
        if (tid < 128 && tid >= off) u = pfx[tid - off];
        __syncthreads();
        if (tid < 128) pfx[tid] += u;
        __syncthreads();
    }
    if (tid < 128) {
        const int node = b * 128 + tid;
        const int ebase = start + pfx[tid] - cnt[tid];
        if (node < N) rowptr[node] = ebase;
        cnt[tid] = ebase;
    }
    if (b == NB - 1 && tid == 0) rowptr[N] = ET;
    __syncthreads();
    for (int i = start + tid; i < end; i += 256) {
        const int val = buck[i];
        const int slot = atomicAdd(&cnt[val >> 16], 1);
        csr[slot] = val & 0xFFFF;
    }
}

// ---- K5: layer-1 edge weights in CSR order (16B/edge). One wave/node.
__global__ __launch_bounds__(256) void k_w1(
    const int* __restrict__ rowptr, const int* __restrict__ csr,
    const float* __restrict__ as1, const float* __restrict__ ad1,
    __half* __restrict__ wc1)
{
    const int lane = threadIdx.x & 63;
    const int n = (blockIdx.x * 256 + threadIdx.x) >> 6;
    const int beg = rowptr[n], end = rowptr[n + 1];
    const float4 b0 = *reinterpret_cast<const float4*>(&ad1[n * HEADS]);
    const float4 b1v = *reinterpret_cast<const float4*>(&ad1[n * HEADS + 4]);
    for (int e = beg + lane; e < end; e += 64) {
        const int s = csr[e];
        const float4 a0 = *reinterpret_cast<const float4*>(&as1[s * HEADS]);
        const float4 a1v = *reinterpret_cast<const float4*>(&as1[s * HEADS + 4]);
        union { float4 f4; __half2 h2[4]; } u;
        u.h2[0] = __floats2half2_rn(__expf(lrelu(a0.x + b0.x)), __expf(lrelu(a0.y + b0.y)));
        u.h2[1] = __floats2half2_rn(__expf(lrelu(a0.z + b0.z)), __expf(lrelu(a0.w + b0.w)));
        u.h2[2] = __floats2half2_rn(__expf(lrelu(a1v.x + b1v.x)), __expf(lrelu(a1v.y + b1v.y)));
        u.h2[3] = __floats2half2_rn(__expf(lrelu(a1v.z + b1v.z)), __expf(lrelu(a1v.w + b1v.w)));
        *reinterpret_cast<float4*>(&wc1[(size_t)e * HEADS]) = u.f4;
    }
}

// ---- K6: layer-1 aggregation. 128 thr/node, 2 ch/thread, unroll 8.
__global__ __launch_bounds__(128) void k_agg1(
    const int* __restrict__ rowptr, const int* __restrict__ csr,
    const __half* __restrict__ h1h, const __half* __restrict__ wc1,
    const float* __restrict__ b1, __half* __restrict__ h1p)
{
    const int n = blockIdx.x;
    const int t = threadIdx.x;
    const int head = t >> 4;
    const int beg = rowptr[n], end = rowptr[n + 1];
    float ax = 0.f, ay = 0.f, accw = 0.f;
    int e = beg;
    for (; e + 7 < end; e += 8) {
        int s[8];
        float w[8];
        float2 f[8];
#pragma unroll
        for (int j = 0; j < 8; j++) s[j] = csr[e + j];
#pragma unroll
        for (int j = 0; j < 8; j++) w[j] = __half2float(wc1[(size_t)(e + j) * HEADS + head]);
#pragma unroll
        for (int j = 0; j < 8; j++)
            f[j] = __half22float2(*reinterpret_cast<const __half2*>(&h1h[(size_t)s[j] * C1 + 2 * t]));
#pragma unroll
        for (int j = 0; j < 8; j++) {
            accw += w[j];
            ax = fmaf(w[j], f[j].x, ax);
            ay = fmaf(w[j], f[j].y, ay);
        }
    }
    for (; e + 3 < end; e += 4) {
        const int s0 = csr[e], s1 = csr[e + 1], s2 = csr[e + 2], s3 = csr[e + 3];
        const float w0 = __half2float(wc1[(size_t)(e + 0) * HEADS + head]);
        const float w1 = __half2float(wc1[(size_t)(e + 1) * HEADS + head]);
        const float w2 = __half2float(wc1[(size_t)(e + 2) * HEADS + head]);
        const float w3 = __half2float(wc1[(size_t)(e + 3) * HEADS + head]);
        const float2 f0 = __half22float2(*reinterpret_cast<const __half2*>(&h1h[(size_t)s0 * C1 + 2 * t]));
        const float2 f1 = __half22float2(*reinterpret_cast<const __half2*>(&h1h[(size_t)s1 * C1 + 2 * t]));
        const float2 f2 = __half22float2(*reinterpret_cast<const __half2*>(&h1h[(size_t)s2 * C1 + 2 * t]));
        const float2 f3 = __half22float2(*reinterpret_cast<const __half2*>(&h1h[(size_t)s3 * C1 + 2 * t]));
        accw += (w0 + w1) + (w2 + w3);
        ax = fmaf(w0, f0.x, ax); ay = fmaf(w0, f0.y, ay);
        ax = fmaf(w1, f1.x, ax); ay = fmaf(w1, f1.y, ay);
        ax = fmaf(w2, f2.x, ax); ay = fmaf(w2, f2.y, ay);
        ax = fmaf(w3, f3.x, ax); ay = fmaf(w3, f3.y, ay);
    }
    for (; e < end; e++) {
        const int s = csr[e];
        const float w = __half2float(wc1[(size_t)e * HEADS + head]);
        const float2 f = __half22float2(*reinterpret_cast<const __half2*>(&h1h[(size_t)s * C1 + 2 * t]));
        accw += w;
        ax = fmaf(w, f.x, ax); ay = fmaf(w, f.y, ay);
    }
    const float inv = 1.f / accw;
    float ox = ax * inv + b1[2 * t];
    float oy = ay * inv + b1[2 * t + 1];
    ox = (ox > 0.f) ? ox : (__expf(ox) - 1.f);
    oy = (oy > 0.f) ? oy : (__expf(oy) - 1.f);
    *reinterpret_cast<__half2*>(&h1p[(size_t)n * C1 + 2 * t]) = __floats2half2_rn(ox, oy);
}

// ---- K7: h2 = h1p @ W2 ; as2/ad2. One wave per 4 nodes.
__global__ __launch_bounds__(256) void k_gemm2(
    const __half* __restrict__ h1p, const float* __restrict__ W2,
    const float* __restrict__ a2s, const float* __restrict__ a2d,
    __half* __restrict__ h2h, float* __restrict__ as2, float* __restrict__ ad2)
{
    const int lane = threadIdx.x & 63;
    const int wid = (blockIdx.x * blockDim.x + threadIdx.x) >> 6;
    const int n0 = wid * 4;
    const int c = lane;
    const int cc = (c < NC) ? c : (NC - 1);
    float acc[4] = {0.f, 0.f, 0.f, 0.f};
    for (int k = 0; k < C1; k += 8) {
        float w[8];
#pragma unroll
        for (int j = 0; j < 8; j++) w[j] = W2[(k + j) * NC + cc];
#pragma unroll
        for (int r = 0; r < 4; r++) {
            union { float4 f4; __half2 h2[4]; } u;
            u.f4 = *reinterpret_cast<const float4*>(&h1p[(size_t)(n0 + r) * C1 + k]);
#pragma unroll
            for (int j = 0; j < 4; j++) {
                const float2 f = __half22float2(u.h2[j]);
                acc[r] = fmaf(f.x, w[2 * j], acc[r]);
                acc[r] = fmaf(f.y, w[2 * j + 1], acc[r]);
            }
        }
    }
    const float a_s = (c < NC) ? a2s[c] : 0.f;
    const float a_d = (c < NC) ? a2d[c] : 0.f;
#pragma unroll
    for (int j = 0; j < 4; j++) {
        const float v = acc[j];
        if (c < NC) h2h[(size_t)(n0 + j) * NC + c] = __float2half(v);
        float ps = (c < NC) ? v * a_s : 0.f;
        float pd = (c < NC) ? v * a_d : 0.f;
#pragma unroll
        for (int off = 32; off >= 1; off >>= 1) {
            ps += __shfl_xor(ps, off);
            pd += __shfl_xor(pd, off);
        }
        if (lane == 0) { as2[n0 + j] = ps; ad2[n0 + j] = pd; }
    }
}

// ---- K8: layer-2 aggregation + bias + log_softmax. One wave/node, unroll 8.
__global__ __launch_bounds__(256) void k_agg2(
    const int* __restrict__ rowptr, const int* __restrict__ csr,
    const __half* __restrict__ h2h, const float* __restrict__ as2,
    const float* __restrict__ ad2, const float* __restrict__ b2,
    float* __restrict__ out)
{
    const int lane = threadIdx.x & 63;
    const int n = (blockIdx.x * blockDim.x + threadIdx.x) >> 6;
    const int c = lane;
    const int cc = (c < NC) ? c : (NC - 1);
    const float adv = ad2[n];
    const int beg = rowptr[n], end = rowptr[n + 1];
    float acc = 0.f, accw = 0.f;
    int e = beg;
    for (; e + 7 < end; e += 8) {
        int s[8];
        float w[8], g[8];
#pragma unroll
        for (int j = 0; j < 8; j++) s[j] = csr[e + j];
#pragma unroll
        for (int j = 0; j < 8; j++) w[j] = __expf(lrelu(as2[s[j]] + adv));
#pragma unroll
        for (int j = 0; j < 8; j++) g[j] = __half2float(h2h[(size_t)s[j] * NC + cc]);
#pragma unroll
        for (int j = 0; j < 8; j++) {
            accw += w[j];
            acc = fmaf(w[j], g[j], acc);
        }
    }
    for (; e + 3 < end; e += 4) {
        const int s0 = csr[e], s1 = csr[e + 1], s2 = csr[e + 2], s3 = csr[e + 3];
        const float w0 = __expf(lrelu(as2[s0] + adv));
        const float w1 = __expf(lrelu(as2[s1] + adv));
        const float w2 = __expf(lrelu(as2[s2] + adv));
        const float w3 = __expf(lrelu(as2[s3] + adv));
        const float g0 = __half2float(h2h[(size_t)s0 * NC + cc]);
        const float g1 = __half2float(h2h[(size_t)s1 * NC + cc]);
        const float g2 = __half2float(h2h[(size_t)s2 * NC + cc]);
        const float g3 = __half2float(h2h[(size_t)s3 * NC + cc]);
        accw += (w0 + w1) + (w2 + w3);
        acc = fmaf(w0, g0, acc);
        acc = fmaf(w1, g1, acc);
        acc = fmaf(w2, g2, acc);
        acc = fmaf(w3, g3, acc);
    }
    for (; e < end; e++) {
        const int s = csr[e];
        const float w = __expf(lrelu(as2[s] + adv));
        accw += w;
        acc = fmaf(w, __half2float(h2h[(size_t)s * NC + cc]), acc);
    }
    const float v = acc / accw + b2[cc];
    float m = (c < NC) ? v : -1e30f;
#pragma unroll
    for (int off = 32; off >= 1; off >>= 1) m = fmaxf(m, __shfl_xor(m, off));
    float S = (c < NC) ? __expf(v - m) : 0.f;
#pragma unroll
    for (int off = 32; off >= 1; off >>= 1) S += __shfl_xor(S, off);
    if (c < NC) out[(size_t)n * NC + c] = v - m - logf(S);
}

extern "C" void kernel_launch(void* const* d_in, const int* in_sizes, int n_in,
                              void* d_out, int out_size, void* d_ws, size_t ws_size,
                              hipStream_t stream)
{
    const float* x   = (const float*)d_in[0];
    const int*   ei  = (const int*)d_in[1];
    const float* W1  = (const float*)d_in[2];
    const float* a1s = (const float*)d_in[3];
    const float* a1d = (const float*)d_in[4];
    const float* b1  = (const float*)d_in[5];
    const float* W2  = (const float*)d_in[6];
    const float* a2s = (const float*)d_in[7];
    const float* a2d = (const float*)d_in[8];
    const float* b2  = (const float*)d_in[9];
    float* out = (float*)d_out;

    const int E  = in_sizes[1] / 2;
    const int ET = E + N;

    auto align64 = [](size_t v) { return (v + 63) & ~(size_t)63; };
    char* ws = (char*)d_ws;
    size_t off = 0;
    _Float16* w1sw = (_Float16*)(ws + off); off = align64(off + (size_t)4096 * 8 * 2);
    __half* h1h = (__half*)(ws + off); off = align64(off + (size_t)N * C1 * 2);
    __half* h1p = (__half*)(ws + off); off = align64(off + (size_t)N * C1 * 2);
    __half* h2h = (__half*)(ws + off); off = align64(off + (size_t)N * NC * 2);
    float* as1 = (float*)(ws + off); off = align64(off + (size_t)N * HEADS * 4);
    float* ad1 = (float*)(ws + off); off = align64(off + (size_t)N * HEADS * 4);
    float* as2 = (float*)(ws + off); off = align64(off + (size_t)N * 4);
    float* ad2 = (float*)(ws + off); off = align64(off + (size_t)N * 4);
    int* hist   = (int*)(ws + off); off = align64(off + (size_t)HM * 4);
    int* bsum   = (int*)(ws + off); off = align64(off + (size_t)NB * 4);
    int* buck   = (int*)(ws + off); off = align64(off + (size_t)ET * 4);
    int* rowptr = (int*)(ws + off); off = align64(off + (size_t)(N + 1) * 4);
    int* csr    = (int*)(ws + off); off = align64(off + (size_t)ET * 4);
    __half* wc1 = (__half*)(ws + off); off = align64(off + (size_t)ET * HEADS * 2);

    k_misc<<<PREPW_BLOCKS + HBLOCKS, 256, 0, stream>>>(W1, w1sw, ei, E, hist);
    k_gemm1_mfma<<<313, 256, 0, stream>>>(x, w1sw, a1s, a1d, h1h, as1, ad1);
    k_bsum<<<NB, 256, 0, stream>>>(hist, bsum);
    k_bscan<<<1, 256, 0, stream>>>(bsum);
    k_hscan<<<NB, 256, 0, stream>>>(hist, bsum);
    k_scatter<<<HBLOCKS, 256, 0, stream>>>(ei, E, hist, buck);
    k_bucket<<<NB, 256, 0, stream>>>(hist, buck, ET, csr, rowptr);
    k_w1<<<5000, 256, 0, stream>>>(rowptr, csr, as1, ad1, wc1);
    k_agg1<<<N, 128, 0, stream>>>(rowptr, csr, h1h, wc1, b1, h1p);
    k_gemm2<<<1250, 256, 0, stream>>>(h1p, W2, a2s, a2d, h2h, as2, ad2);
    k_agg2<<<5000, 256, 0, stream>>>(rowptr, csr, h2h, as2, ad2, b2, out);
}